// Round 1
// baseline (1683.787 us; speedup 1.0000x reference)
//
#include <hip/hip_runtime.h>

#define CDIM 256
#define WDIM 64
#define NBH  2048
#define XS_STRIDE 260   // 64-row X tile, row-major, +4 pad (bank spread, 16B aligned)
#define TS_STRIDE 260   // T / V tile, row-major
#define SS_STRIDE 68    // 64x64 logits/probs, +4 pad

// ---------------------------------------------------------------------------
// Prep: M = Wk @ Wq^T  (M[c][d] = sum_f Wk[c][f]*Wq[d][f]),
//       bvec[d] = sum_f Wq[d][f]*bk[f]   (the only bias term that survives
//       softmax row-invariance).
// ---------------------------------------------------------------------------
__global__ __launch_bounds__(256) void prep_kernel(
    const float* __restrict__ wq, const float* __restrict__ wk,
    const float* __restrict__ bk, float* __restrict__ M,
    float* __restrict__ bvec)
{
    __shared__ float s_row[CDIM];
    const int t = threadIdx.x;
    const int blk = blockIdx.x;
    if (blk < CDIM) {
        s_row[t] = wk[blk * CDIM + t];
        __syncthreads();
        const float* wqrow = wq + t * CDIM;
        float acc = 0.f;
        #pragma unroll 8
        for (int f = 0; f < CDIM; ++f) acc = fmaf(s_row[f], wqrow[f], acc);
        M[blk * CDIM + t] = acc;
    } else {
        const float* wqrow = wq + t * CDIM;
        float acc = 0.f;
        #pragma unroll 8
        for (int f = 0; f < CDIM; ++f) acc = fmaf(wqrow[f], bk[f], acc);
        bvec[t] = acc;
    }
}

// ---------------------------------------------------------------------------
// Main: one block per (b,h). LDS: X (64x256), T=X@M then V=X@Wv (64x256),
// S (64x64). All fp32 vector FMA (no fp32 MFMA on CDNA4).
// ---------------------------------------------------------------------------
extern __shared__ float smem[];

__global__ __launch_bounds__(256) void attn_kernel(
    const float* __restrict__ x, const float* __restrict__ M,
    const float* __restrict__ bvec, const float* __restrict__ wv,
    const float* __restrict__ bv, float* __restrict__ out)
{
    float* sXs = smem;                          // [64][XS_STRIDE]
    float* sTs = sXs + WDIM * XS_STRIDE;        // [64][TS_STRIDE]  (T, later V)
    float* sSs = sTs + WDIM * TS_STRIDE;        // [64][SS_STRIDE]
    float* sxb = sSs + WDIM * SS_STRIDE;        // [64]

    const int t = threadIdx.x;
    const int bh = blockIdx.x;
    const float* __restrict__ xblk = x + (size_t)bh * (WDIM * CDIM);
    float* __restrict__ oblk = out + (size_t)bh * (WDIM * CDIM);

    // ---- Phase 1: load X tile (row-major, padded) -------------------------
    {
        const float4* xv4 = (const float4*)xblk;
        #pragma unroll
        for (int n = 0; n < 16; ++n) {
            int idx = n * 256 + t;          // 0..4095 float4s
            float4 v = xv4[idx];
            int i = idx >> 6;               // 64 float4 per row
            int c = (idx & 63) << 2;
            *(float4*)&sXs[i * XS_STRIDE + c] = v;
        }
    }
    __syncthreads();

    // ---- xb[j] = x_j . bvec  (wave 0 only; visible after phase-2 barrier) -
    if (t < WDIM) {
        float acc = 0.f;
        #pragma unroll 4
        for (int c = 0; c < CDIM; c += 4) {
            float4 xv = *(const float4*)&sXs[t * XS_STRIDE + c];
            float4 b4 = *(const float4*)&bvec[c];
            acc = fmaf(xv.x, b4.x, acc);
            acc = fmaf(xv.y, b4.y, acc);
            acc = fmaf(xv.z, b4.z, acc);
            acc = fmaf(xv.w, b4.w, acc);
        }
        sxb[t] = acc;
    }

    const int r    = t >> 5;                // 0..7 : rows r*8..r*8+7
    const int cg   = t & 31;                // 0..31
    const int col0 = cg << 2;               // cols col0..col0+3
    const int col1 = (cg << 2) + 128;       // cols col1..col1+3 (coalesced stores)

    // ---- Phase 2: T = X @ M  (outer product over c) -----------------------
    {
        float acc[8][8];
        #pragma unroll
        for (int a = 0; a < 8; ++a)
            #pragma unroll
            for (int b = 0; b < 8; ++b) acc[a][b] = 0.f;

        #pragma unroll 4
        for (int c = 0; c < CDIM; ++c) {
            float xk[8];
            #pragma unroll
            for (int k = 0; k < 8; ++k) xk[k] = sXs[(r * 8 + k) * XS_STRIDE + c];
            float4 m0 = *(const float4*)&M[c * CDIM + col0];
            float4 m1 = *(const float4*)&M[c * CDIM + col1];
            float mm[8] = {m0.x, m0.y, m0.z, m0.w, m1.x, m1.y, m1.z, m1.w};
            #pragma unroll
            for (int k = 0; k < 8; ++k)
                #pragma unroll
                for (int m = 0; m < 8; ++m)
                    acc[k][m] = fmaf(xk[k], mm[m], acc[k][m]);
        }
        #pragma unroll
        for (int k = 0; k < 8; ++k) {
            float4 w0 = make_float4(acc[k][0], acc[k][1], acc[k][2], acc[k][3]);
            float4 w1 = make_float4(acc[k][4], acc[k][5], acc[k][6], acc[k][7]);
            *(float4*)&sTs[(r * 8 + k) * TS_STRIDE + col0] = w0;
            *(float4*)&sTs[(r * 8 + k) * TS_STRIDE + col1] = w1;
        }
    }
    __syncthreads();

    // ---- Phase 3: S = T @ X^T + xb  (inner product; X row reads broadcast)
    {
        const int i3 = t & 63;
        const int jg = t >> 6;              // 16 cols per thread
        float acc[16];
        #pragma unroll
        for (int u = 0; u < 16; ++u) acc[u] = 0.f;

        #pragma unroll 2
        for (int d = 0; d < CDIM; d += 4) {
            float4 tv = *(const float4*)&sTs[i3 * TS_STRIDE + d];
            #pragma unroll
            for (int u = 0; u < 16; ++u) {
                float4 xv = *(const float4*)&sXs[(jg * 16 + u) * XS_STRIDE + d];
                acc[u] = fmaf(tv.x, xv.x, acc[u]);
                acc[u] = fmaf(tv.y, xv.y, acc[u]);
                acc[u] = fmaf(tv.z, xv.z, acc[u]);
                acc[u] = fmaf(tv.w, xv.w, acc[u]);
            }
        }
        #pragma unroll
        for (int q = 0; q < 4; ++q) {
            int j = jg * 16 + q * 4;
            float4 w = make_float4(acc[q*4+0] + sxb[j+0], acc[q*4+1] + sxb[j+1],
                                   acc[q*4+2] + sxb[j+2], acc[q*4+3] + sxb[j+3]);
            *(float4*)&sSs[i3 * SS_STRIDE + j] = w;
        }
    }
    __syncthreads();

    // ---- Phase 4: row softmax (4 lanes per row, quad shuffle reduce) ------
    {
        const int row = t >> 2, part = t & 3;
        float* srow = &sSs[row * SS_STRIDE + part * 16];
        float mx = srow[0];
        #pragma unroll
        for (int u = 1; u < 16; ++u) mx = fmaxf(mx, srow[u]);
        mx = fmaxf(mx, __shfl_xor(mx, 1));
        mx = fmaxf(mx, __shfl_xor(mx, 2));
        float e[16], sum = 0.f;
        #pragma unroll
        for (int u = 0; u < 16; ++u) { e[u] = __expf(srow[u] - mx); sum += e[u]; }
        sum += __shfl_xor(sum, 1);
        sum += __shfl_xor(sum, 2);
        float inv = 1.0f / sum;
        #pragma unroll
        for (int u = 0; u < 16; ++u) srow[u] = e[u] * inv;
    }
    __syncthreads();

    // ---- Phase 5: V = X @ Wv + bv  (into the T buffer) --------------------
    {
        float acc[8][8];
        #pragma unroll
        for (int a = 0; a < 8; ++a)
            #pragma unroll
            for (int b = 0; b < 8; ++b) acc[a][b] = 0.f;

        #pragma unroll 4
        for (int c = 0; c < CDIM; ++c) {
            float xk[8];
            #pragma unroll
            for (int k = 0; k < 8; ++k) xk[k] = sXs[(r * 8 + k) * XS_STRIDE + c];
            float4 w0 = *(const float4*)&wv[c * CDIM + col0];
            float4 w1 = *(const float4*)&wv[c * CDIM + col1];
            float mm[8] = {w0.x, w0.y, w0.z, w0.w, w1.x, w1.y, w1.z, w1.w};
            #pragma unroll
            for (int k = 0; k < 8; ++k)
                #pragma unroll
                for (int m = 0; m < 8; ++m)
                    acc[k][m] = fmaf(xk[k], mm[m], acc[k][m]);
        }
        float4 b0 = *(const float4*)&bv[col0];
        float4 b1 = *(const float4*)&bv[col1];
        #pragma unroll
        for (int k = 0; k < 8; ++k) {
            float4 w0 = make_float4(acc[k][0] + b0.x, acc[k][1] + b0.y,
                                    acc[k][2] + b0.z, acc[k][3] + b0.w);
            float4 w1 = make_float4(acc[k][4] + b1.x, acc[k][5] + b1.y,
                                    acc[k][6] + b1.z, acc[k][7] + b1.w);
            *(float4*)&sTs[(r * 8 + k) * TS_STRIDE + col0] = w0;
            *(float4*)&sTs[(r * 8 + k) * TS_STRIDE + col1] = w1;
        }
    }
    __syncthreads();

    // ---- Phase 6: out = (P @ V) * x ---------------------------------------
    {
        float acc[8][8];
        #pragma unroll
        for (int a = 0; a < 8; ++a)
            #pragma unroll
            for (int b = 0; b < 8; ++b) acc[a][b] = 0.f;

        #pragma unroll 2
        for (int j = 0; j < WDIM; ++j) {
            float pk[8];
            #pragma unroll
            for (int k = 0; k < 8; ++k) pk[k] = sSs[(r * 8 + k) * SS_STRIDE + j];
            float4 v0 = *(const float4*)&sTs[j * TS_STRIDE + col0];
            float4 v1 = *(const float4*)&sTs[j * TS_STRIDE + col1];
            float vm[8] = {v0.x, v0.y, v0.z, v0.w, v1.x, v1.y, v1.z, v1.w};
            #pragma unroll
            for (int k = 0; k < 8; ++k)
                #pragma unroll
                for (int m = 0; m < 8; ++m)
                    acc[k][m] = fmaf(pk[k], vm[m], acc[k][m]);
        }
        #pragma unroll
        for (int k = 0; k < 8; ++k) {
            int i = r * 8 + k;
            float4 x0 = *(const float4*)&xblk[i * CDIM + col0];  // gate (L2-hot)
            float4 x1 = *(const float4*)&xblk[i * CDIM + col1];
            float4 o0 = make_float4(acc[k][0] * x0.x, acc[k][1] * x0.y,
                                    acc[k][2] * x0.z, acc[k][3] * x0.w);
            float4 o1 = make_float4(acc[k][4] * x1.x, acc[k][5] * x1.y,
                                    acc[k][6] * x1.z, acc[k][7] * x1.w);
            *(float4*)&oblk[i * CDIM + col0] = o0;
            *(float4*)&oblk[i * CDIM + col1] = o1;
        }
    }
}

extern "C" void kernel_launch(void* const* d_in, const int* in_sizes, int n_in,
                              void* d_out, int out_size, void* d_ws, size_t ws_size,
                              hipStream_t stream) {
    const float* x  = (const float*)d_in[0];
    const float* wq = (const float*)d_in[1];
    // d_in[2] = bq: softmax-row-invariant, provably unused
    const float* wk = (const float*)d_in[3];
    const float* bk = (const float*)d_in[4];
    const float* wv = (const float*)d_in[5];
    const float* bv = (const float*)d_in[6];
    float* out  = (float*)d_out;
    float* M    = (float*)d_ws;             // 256*256 floats
    float* bvec = M + CDIM * CDIM;          // 256 floats

    prep_kernel<<<CDIM + 1, CDIM, 0, stream>>>(wq, wk, bk, M, bvec);

    const size_t lds = (size_t)(WDIM * XS_STRIDE + WDIM * TS_STRIDE +
                                WDIM * SS_STRIDE + WDIM) * sizeof(float);
    hipFuncSetAttribute((const void*)attn_kernel,
                        hipFuncAttributeMaxDynamicSharedMemorySize, (int)lds);
    attn_kernel<<<NBH, 256, lds, stream>>>(x, M, bvec, wv, bv, out);
}

// Round 2
// 496.122 us; speedup vs baseline: 3.3939x; 3.3939x over previous
//
#include <hip/hip_runtime.h>

#define CD   256
#define WD   64
#define NBH  2048
#define XST  264   // bf16 row stride for X/T tiles (256 + 8: balanced banks for b128)
#define VST  72    // bf16 row stride for Vt (64 + 8)
#define SST  68    // fp32 row stride for S (64 + 4)

typedef unsigned short u16;
typedef __attribute__((ext_vector_type(8))) short bfrag_t;  // 8 bf16 = 4 VGPR
typedef __attribute__((ext_vector_type(4))) float f4_t;

#define MFMA(a, b, c) __builtin_amdgcn_mfma_f32_16x16x32_bf16(a, b, c, 0, 0, 0)

__device__ __forceinline__ u16 f2bf(float f) {
    unsigned u = __float_as_uint(f);
    u += 0x7fffu + ((u >> 16) & 1u);          // round-to-nearest-even
    return (u16)(u >> 16);
}
__device__ __forceinline__ float bf2f(u16 h) {
    return __uint_as_float(((unsigned)h) << 16);
}

// ---------------------------------------------------------------------------
// Prep: Mt[d][c] = sum_f wk[c][f]*wq[d][f]  (= (Wk Wq^T)^T entry), split hi/lo
//       Wvt[d][c] = wv[c][d] (bf16), wqbk[d] = sum_f wq[d][f]*bk[f] (fp32)
// ---------------------------------------------------------------------------
__global__ __launch_bounds__(256) void prep_kernel(
    const float* __restrict__ wq, const float* __restrict__ wk,
    const float* __restrict__ bk, const float* __restrict__ wv,
    u16* __restrict__ Mthi, u16* __restrict__ Mtlo,
    u16* __restrict__ Wvthi, float* __restrict__ wqbk)
{
    const int t = threadIdx.x, blk = blockIdx.x;
    if (blk < CD) {
        __shared__ float swq[CD];
        swq[t] = wq[blk * CD + t];
        __syncthreads();
        const float* wkr = wk + t * CD;        // row c = t
        float acc = 0.f;
        #pragma unroll 8
        for (int f = 0; f < CD; ++f) acc = fmaf(wkr[f], swq[f], acc);
        u16 h = f2bf(acc);
        Mthi[blk * CD + t] = h;
        Mtlo[blk * CD + t] = f2bf(acc - bf2f(h));
        Wvthi[blk * CD + t] = f2bf(wv[t * CD + blk]);
    } else {
        const float* wqr = wq + t * CD;
        float acc = 0.f;
        #pragma unroll 8
        for (int f = 0; f < CD; ++f) acc = fmaf(wqr[f], bk[f], acc);
        wqbk[t] = acc;
    }
}

// ---------------------------------------------------------------------------
// Main: one block per (b,h). All matmuls are A·B^T-form MFMA (row-major
// contiguous 8-bf16 frags). Split-precision bf16 for the logit path.
// ---------------------------------------------------------------------------
extern __shared__ char smem_raw[];

__global__ __launch_bounds__(256, 1) void attn_kernel(
    const float* __restrict__ x,
    const u16* __restrict__ Mthi, const u16* __restrict__ Mtlo,
    const u16* __restrict__ Wvthi, const float* __restrict__ wqbk,
    const float* __restrict__ bv, float* __restrict__ out)
{
    u16* sXhi = (u16*)smem_raw;                 // [64][XST]
    u16* sXlo = sXhi + WD * XST;
    u16* sThi = sXlo + WD * XST;                // [64][XST]  (token-major T)
    u16* sTlo = sThi + WD * XST;
    u16* sVt  = sThi;                           // alias: [256][VST] after S done
    float* sS  = (float*)(sTlo + WD * XST);     // [64][SST]
    float* sxb = sS + WD * SST;                 // [64]
    float* sbv = sxb + WD;                      // [256]

    const int t = threadIdx.x;
    const int wave = t >> 6, lane = t & 63;
    const int lane15 = lane & 15, quad = lane >> 4;
    const int bh = blockIdx.x;
    const float* __restrict__ xblk = x + (size_t)bh * (WD * CD);
    float* __restrict__ oblk = out + (size_t)bh * (WD * CD);

    // ---- stage X -> bf16 hi/lo in LDS; bv -> LDS --------------------------
    sbv[t] = bv[t];
    {
        const float4* xv4 = (const float4*)xblk;
        #pragma unroll
        for (int n = 0; n < 16; ++n) {
            int idx = n * 256 + t;
            float4 v = xv4[idx];
            int i = idx >> 6;
            int c = (idx & 63) << 2;
            ushort4 h4, l4;
            h4.x = f2bf(v.x); l4.x = f2bf(v.x - bf2f(h4.x));
            h4.y = f2bf(v.y); l4.y = f2bf(v.y - bf2f(h4.y));
            h4.z = f2bf(v.z); l4.z = f2bf(v.z - bf2f(h4.z));
            h4.w = f2bf(v.w); l4.w = f2bf(v.w - bf2f(h4.w));
            *(ushort4*)&sXhi[i * XST + c] = h4;
            *(ushort4*)&sXlo[i * XST + c] = l4;
        }
    }
    // ---- xb[v] = x_v . (Wq bk)  (fp32, from global x: L2-hot) -------------
    {
        const int row = t >> 2, part = t & 3;
        const float* xr = xblk + row * CD + part * 64;
        const float* br = wqbk + part * 64;
        float a = 0.f;
        #pragma unroll
        for (int i = 0; i < 16; ++i) {
            float4 xv = *(const float4*)&xr[i * 4];
            float4 bvv = *(const float4*)&br[i * 4];
            a = fmaf(xv.x, bvv.x, a); a = fmaf(xv.y, bvv.y, a);
            a = fmaf(xv.z, bvv.z, a); a = fmaf(xv.w, bvv.w, a);
        }
        a += __shfl_xor(a, 1);
        a += __shfl_xor(a, 2);
        if (part == 0) sxb[row] = a;
    }
    __syncthreads();

    // ---- Phase T: Tt[d][i] = sum_c Mt[d][c] * X[i][c]  (split, 3 terms) ---
    // Wave w: d-tiles w*4..w*4+3, all 4 token-tiles. D: m=d, n=i.
    {
        f4_t acc[4][4];
        const f4_t z = {0.f, 0.f, 0.f, 0.f};
        #pragma unroll
        for (int a = 0; a < 4; ++a)
            #pragma unroll
            for (int b = 0; b < 4; ++b) acc[a][b] = z;

        const int drow = wave * 64 + lane15;
        #pragma unroll
        for (int kk = 0; kk < 8; ++kk) {
            const int k0 = kk * 32 + quad * 8;
            bfrag_t Ah[4], Al[4], Bh[4], Bl[4];
            #pragma unroll
            for (int mt = 0; mt < 4; ++mt) {
                const int off = (drow + mt * 16) * CD + k0;
                Ah[mt] = *(const bfrag_t*)(Mthi + off);
                Al[mt] = *(const bfrag_t*)(Mtlo + off);
            }
            #pragma unroll
            for (int nt = 0; nt < 4; ++nt) {
                const int xo = (nt * 16 + lane15) * XST + k0;
                Bh[nt] = *(const bfrag_t*)(sXhi + xo);
                Bl[nt] = *(const bfrag_t*)(sXlo + xo);
            }
            #pragma unroll
            for (int mt = 0; mt < 4; ++mt)
                #pragma unroll
                for (int nt = 0; nt < 4; ++nt) {
                    acc[mt][nt] = MFMA(Ah[mt], Bh[nt], acc[mt][nt]);
                    acc[mt][nt] = MFMA(Ah[mt], Bl[nt], acc[mt][nt]);
                    acc[mt][nt] = MFMA(Al[mt], Bh[nt], acc[mt][nt]);
                }
        }
        // store T token-major [i][d], split hi/lo (packed 4 consecutive d)
        #pragma unroll
        for (int mt = 0; mt < 4; ++mt)
            #pragma unroll
            for (int nt = 0; nt < 4; ++nt) {
                const int i  = nt * 16 + lane15;
                const int d0 = wave * 64 + mt * 16 + quad * 4;
                ushort4 h4, l4;
                float f;
                f = acc[mt][nt][0]; h4.x = f2bf(f); l4.x = f2bf(f - bf2f(h4.x));
                f = acc[mt][nt][1]; h4.y = f2bf(f); l4.y = f2bf(f - bf2f(h4.y));
                f = acc[mt][nt][2]; h4.z = f2bf(f); l4.z = f2bf(f - bf2f(h4.z));
                f = acc[mt][nt][3]; h4.w = f2bf(f); l4.w = f2bf(f - bf2f(h4.w));
                *(ushort4*)&sThi[i * XST + d0] = h4;
                *(ushort4*)&sTlo[i * XST + d0] = l4;
            }
    }
    __syncthreads();

    // ---- Phase S: S[w][v] = sum_c T[w][c]*X[v][c] + xb[v]  (3 terms) ------
    // Wave w: key-rows w*16..w*16+15 (m), all 4 v-tiles (n).
    {
        f4_t acc[4];
        const f4_t z = {0.f, 0.f, 0.f, 0.f};
        #pragma unroll
        for (int a = 0; a < 4; ++a) acc[a] = z;

        const int m0 = wave * 16;
        #pragma unroll
        for (int kk = 0; kk < 8; ++kk) {
            const int k0 = kk * 32 + quad * 8;
            const int to = (m0 + lane15) * XST + k0;
            bfrag_t Th = *(const bfrag_t*)(sThi + to);
            bfrag_t Tl = *(const bfrag_t*)(sTlo + to);
            #pragma unroll
            for (int nt = 0; nt < 4; ++nt) {
                const int xo = (nt * 16 + lane15) * XST + k0;
                bfrag_t Xh = *(const bfrag_t*)(sXhi + xo);
                bfrag_t Xl = *(const bfrag_t*)(sXlo + xo);
                acc[nt] = MFMA(Th, Xh, acc[nt]);
                acc[nt] = MFMA(Th, Xl, acc[nt]);
                acc[nt] = MFMA(Tl, Xh, acc[nt]);
            }
        }
        #pragma unroll
        for (int nt = 0; nt < 4; ++nt) {
            const int v = nt * 16 + lane15;
            const float xbv = sxb[v];
            #pragma unroll
            for (int r = 0; r < 4; ++r) {
                const int wtok = m0 + quad * 4 + r;
                sS[wtok * SST + v] = acc[nt][r] + xbv;
            }
        }
    }
    __syncthreads();

    // ---- Phase V: Vt[d][j] = sum_c Wvt[d][c]*Xhi[j][c] + bv[d]  (1 term) --
    // (overwrites T region; T fully consumed above). Then softmax on sS.
    {
        f4_t acc[4][4];
        const f4_t z = {0.f, 0.f, 0.f, 0.f};
        #pragma unroll
        for (int a = 0; a < 4; ++a)
            #pragma unroll
            for (int b = 0; b < 4; ++b) acc[a][b] = z;

        const int drow = wave * 64 + lane15;
        #pragma unroll
        for (int kk = 0; kk < 8; ++kk) {
            const int k0 = kk * 32 + quad * 8;
            bfrag_t Af[4], Bf[4];
            #pragma unroll
            for (int mt = 0; mt < 4; ++mt)
                Af[mt] = *(const bfrag_t*)(Wvthi + (drow + mt * 16) * CD + k0);
            #pragma unroll
            for (int nt = 0; nt < 4; ++nt)
                Bf[nt] = *(const bfrag_t*)(sXhi + (nt * 16 + lane15) * XST + k0);
            #pragma unroll
            for (int mt = 0; mt < 4; ++mt)
                #pragma unroll
                for (int nt = 0; nt < 4; ++nt)
                    acc[mt][nt] = MFMA(Af[mt], Bf[nt], acc[mt][nt]);
        }
        #pragma unroll
        for (int mt = 0; mt < 4; ++mt)
            #pragma unroll
            for (int nt = 0; nt < 4; ++nt) {
                const int j = nt * 16 + lane15;
                #pragma unroll
                for (int r = 0; r < 4; ++r) {
                    const int d = wave * 64 + mt * 16 + quad * 4 + r;
                    sVt[d * VST + j] = f2bf(acc[mt][nt][r] + sbv[d]);
                }
            }
    }
    // ---- softmax over v (axis -1): 4 lanes per row, fp32 in sS ------------
    {
        const int row = t >> 2, part = t & 3;
        float* srow = &sS[row * SST + part * 16];
        float mx = srow[0];
        #pragma unroll
        for (int u = 1; u < 16; ++u) mx = fmaxf(mx, srow[u]);
        mx = fmaxf(mx, __shfl_xor(mx, 1));
        mx = fmaxf(mx, __shfl_xor(mx, 2));
        float e[16], sum = 0.f;
        #pragma unroll
        for (int u = 0; u < 16; ++u) { e[u] = __expf(srow[u] - mx); sum += e[u]; }
        sum += __shfl_xor(sum, 1);
        sum += __shfl_xor(sum, 2);
        float inv = 1.0f / sum;
        #pragma unroll
        for (int u = 0; u < 16; ++u) srow[u] = e[u] * inv;
    }
    __syncthreads();

    // ---- Phase PV: out[w][d] = (sum_j P[w][j] * Vt[d][j]) * x[w][d] -------
    // Wave w: all 4 token-tiles (m), d-tiles w*4..w*4+3 (n).
    {
        f4_t acc[4][4];
        const f4_t z = {0.f, 0.f, 0.f, 0.f};
        #pragma unroll
        for (int a = 0; a < 4; ++a)
            #pragma unroll
            for (int b = 0; b < 4; ++b) acc[a][b] = z;

        const int nbase = wave * 64;
        #pragma unroll
        for (int kk = 0; kk < 2; ++kk) {
            const int k0 = kk * 32 + quad * 8;
            bfrag_t Af[4], Bf[4];
            #pragma unroll
            for (int mt = 0; mt < 4; ++mt) {
                const float* p = &sS[(mt * 16 + lane15) * SST + k0];
                f4_t p0 = *(const f4_t*)p;
                f4_t p1 = *(const f4_t*)(p + 4);
                bfrag_t a;
                a[0] = (short)f2bf(p0[0]); a[1] = (short)f2bf(p0[1]);
                a[2] = (short)f2bf(p0[2]); a[3] = (short)f2bf(p0[3]);
                a[4] = (short)f2bf(p1[0]); a[5] = (short)f2bf(p1[1]);
                a[6] = (short)f2bf(p1[2]); a[7] = (short)f2bf(p1[3]);
                Af[mt] = a;
            }
            #pragma unroll
            for (int nt = 0; nt < 4; ++nt)
                Bf[nt] = *(const bfrag_t*)(sVt + (nbase + nt * 16 + lane15) * VST + k0);
            #pragma unroll
            for (int mt = 0; mt < 4; ++mt)
                #pragma unroll
                for (int nt = 0; nt < 4; ++nt)
                    acc[mt][nt] = MFMA(Af[mt], Bf[nt], acc[mt][nt]);
        }
        #pragma unroll
        for (int mt = 0; mt < 4; ++mt)
            #pragma unroll
            for (int nt = 0; nt < 4; ++nt) {
                const int d = nbase + nt * 16 + lane15;
                #pragma unroll
                for (int r = 0; r < 4; ++r) {
                    const int wtok = mt * 16 + quad * 4 + r;
                    float g = xblk[wtok * CD + d];
                    oblk[wtok * CD + d] = acc[mt][nt][r] * g;
                }
            }
    }
}

extern "C" void kernel_launch(void* const* d_in, const int* in_sizes, int n_in,
                              void* d_out, int out_size, void* d_ws, size_t ws_size,
                              hipStream_t stream) {
    const float* x  = (const float*)d_in[0];
    const float* wq = (const float*)d_in[1];
    // d_in[2] = bq: row-constant in softmax -> provably unused
    const float* wk = (const float*)d_in[3];
    const float* bk = (const float*)d_in[4];
    const float* wv = (const float*)d_in[5];
    const float* bv = (const float*)d_in[6];
    float* out = (float*)d_out;

    char* ws = (char*)d_ws;
    u16* Mthi   = (u16*)ws;                         // 128 KB
    u16* Mtlo   = (u16*)(ws + (128 << 10));         // 128 KB
    u16* Wvthi  = (u16*)(ws + (256 << 10));         // 128 KB
    float* wqbk = (float*)(ws + (384 << 10));       // 1 KB

    prep_kernel<<<CD + 1, 256, 0, stream>>>(wq, wk, bk, wv, Mthi, Mtlo, Wvthi, wqbk);

    const size_t lds = (size_t)(4 * WD * XST * sizeof(u16)) +
                       (WD * SST + WD + CD) * sizeof(float);
    hipFuncSetAttribute((const void*)attn_kernel,
                        hipFuncAttributeMaxDynamicSharedMemorySize, (int)lds);
    attn_kernel<<<NBH, 256, lds, stream>>>(x, Mthi, Mtlo, Wvthi, wqbk, bv, out);
}

// Round 3
// 374.786 us; speedup vs baseline: 4.4927x; 1.3237x over previous
//
#include <hip/hip_runtime.h>

#define CD   256
#define WD   64
#define NBH  2048
#define XST  264   // bf16 row stride for X/T tiles (256+8, keeps rows 16B-aligned)
#define VST  72    // bf16 row stride for Vt (64+8)
#define SST  68    // fp32 row stride for S (64+4)

typedef unsigned short u16;
typedef __attribute__((ext_vector_type(8))) short bfrag_t;  // 8 bf16 = 4 VGPR
typedef __attribute__((ext_vector_type(4))) float f4_t;

#define MFMA(a, b, c) __builtin_amdgcn_mfma_f32_16x16x32_bf16(a, b, c, 0, 0, 0)

__device__ __forceinline__ u16 f2bf(float f) {
    unsigned u = __float_as_uint(f);
    u += 0x7fffu + ((u >> 16) & 1u);          // round-to-nearest-even
    return (u16)(u >> 16);
}
__device__ __forceinline__ float bf2f(u16 h) {
    return __uint_as_float(((unsigned)h) << 16);
}

// ---------------------------------------------------------------------------
// prep_m: Mt[d][c] = sum_f wk[c][f]*wq[d][f], split hi/lo bf16.
// Grid 128: blockIdx = d-tile(16) * 8 + c-tile(8 tiles of 32 c). All global
// reads coalesced via LDS staging.
// ---------------------------------------------------------------------------
__global__ __launch_bounds__(256) void prep_m(
    const float* __restrict__ wq, const float* __restrict__ wk,
    u16* __restrict__ Mthi, u16* __restrict__ Mtlo)
{
    __shared__ float swq[16 * 257];
    __shared__ float swk[32 * 257];
    const int t = threadIdx.x;
    const int dt = blockIdx.x >> 3;   // 16 d-tiles
    const int ct = blockIdx.x & 7;    // 8 c-tiles (32 c each)
    #pragma unroll
    for (int n = 0; n < 16; ++n) {
        int idx = n * 256 + t;        // 4096
        int d = idx >> 8, f = idx & 255;
        swq[d * 257 + f] = wq[(dt * 16 + d) * CD + f];
    }
    #pragma unroll
    for (int n = 0; n < 32; ++n) {
        int idx = n * 256 + t;        // 8192
        int c = idx >> 8, f = idx & 255;
        swk[c * 257 + f] = wk[(ct * 32 + c) * CD + f];
    }
    __syncthreads();
    const int d = t & 15, c0 = (t >> 4) * 2;
    #pragma unroll
    for (int cc = 0; cc < 2; ++cc) {
        const float* kr = &swk[(c0 + cc) * 257];
        const float* qr = &swq[d * 257];
        float acc = 0.f;
        #pragma unroll 8
        for (int f = 0; f < CD; ++f) acc = fmaf(kr[f], qr[f], acc);
        u16 h = f2bf(acc);
        int off = (dt * 16 + d) * CD + ct * 32 + c0 + cc;
        Mthi[off] = h;
        Mtlo[off] = f2bf(acc - bf2f(h));
    }
}

// prep_v: Wvt[d][c] = bf16(wv[c][d]) via LDS transpose. Grid 16 (4x4 tiles).
__global__ __launch_bounds__(256) void prep_v(
    const float* __restrict__ wv, u16* __restrict__ Wvthi)
{
    __shared__ float tile[64 * 65];
    const int t = threadIdx.x;
    const int bc = blockIdx.x >> 2, bd = blockIdx.x & 3;
    #pragma unroll
    for (int n = 0; n < 16; ++n) {
        int idx = n * 256 + t;
        int c = idx >> 6, d = idx & 63;
        tile[c * 65 + d] = wv[(bc * 64 + c) * CD + bd * 64 + d];
    }
    __syncthreads();
    #pragma unroll
    for (int n = 0; n < 16; ++n) {
        int idx = n * 256 + t;
        int d = idx >> 6, c = idx & 63;
        Wvthi[(bd * 64 + d) * CD + bc * 64 + c] = f2bf(tile[c * 65 + d]);
    }
}

// prep_b: wqbk[c] = sum_f wq[c][f]*bk[f]. Grid 16, coalesced, 16-lane reduce.
__global__ __launch_bounds__(256) void prep_b(
    const float* __restrict__ wq, const float* __restrict__ bk,
    float* __restrict__ wqbk)
{
    __shared__ float sbk[CD];
    const int t = threadIdx.x;
    if (t < CD) sbk[t] = bk[t];
    __syncthreads();
    const int c = blockIdx.x * 16 + (t >> 4), part = t & 15;
    const float* wr = wq + c * CD + part * 16;
    const float* br = sbk + part * 16;
    float a = 0.f;
    #pragma unroll
    for (int j = 0; j < 16; ++j) a = fmaf(wr[j], br[j], a);
    a += __shfl_xor(a, 1);
    a += __shfl_xor(a, 2);
    a += __shfl_xor(a, 4);
    a += __shfl_xor(a, 8);
    if (part == 0) wqbk[c] = a;
}

// ---------------------------------------------------------------------------
// Main: one block per (b,h), 1024 threads = 16 waves (4 waves/SIMD at
// 1 block/CU — the occupancy fix). Split-precision bf16 logit path.
// ---------------------------------------------------------------------------
extern __shared__ char smem_raw[];

__global__ __launch_bounds__(1024, 4) void attn_kernel(
    const float* __restrict__ x,
    const u16* __restrict__ Mthi, const u16* __restrict__ Mtlo,
    const u16* __restrict__ Wvthi, const float* __restrict__ wqbk,
    const float* __restrict__ bv, float* __restrict__ out)
{
    u16* sXhi = (u16*)smem_raw;                 // [64][XST]
    u16* sXlo = sXhi + WD * XST;
    u16* sThi = sXlo + WD * XST;                // [64][XST] token-major T
    u16* sTlo = sThi + WD * XST;
    u16* sVt  = sThi;                           // alias: [256][VST] after S
    float* sS  = (float*)(sTlo + WD * XST);     // [64][SST]
    float* sxb = sS + WD * SST;                 // [64]
    float* sbv = sxb + WD;                      // [256]

    const int t = threadIdx.x;
    const int wave = t >> 6, lane = t & 63;
    const int lane15 = lane & 15, quad = lane >> 4;
    const int bh = blockIdx.x;
    const float* __restrict__ xblk = x + (size_t)bh * (WD * CD);
    float* __restrict__ oblk = out + (size_t)bh * (WD * CD);

    if (t < CD) sbv[t] = bv[t];
    // ---- stage X -> bf16 hi/lo --------------------------------------------
    {
        const float4* xv4 = (const float4*)xblk;
        #pragma unroll
        for (int n = 0; n < 4; ++n) {
            int idx = n * 1024 + t;             // 0..4095
            float4 v = xv4[idx];
            int i = idx >> 6;
            int c = (idx & 63) << 2;
            ushort4 h4, l4;
            h4.x = f2bf(v.x); l4.x = f2bf(v.x - bf2f(h4.x));
            h4.y = f2bf(v.y); l4.y = f2bf(v.y - bf2f(h4.y));
            h4.z = f2bf(v.z); l4.z = f2bf(v.z - bf2f(h4.z));
            h4.w = f2bf(v.w); l4.w = f2bf(v.w - bf2f(h4.w));
            *(ushort4*)&sXhi[i * XST + c] = h4;
            *(ushort4*)&sXlo[i * XST + c] = l4;
        }
    }
    // ---- xb[v] = x_v . (Wq bk)  (fp32, 16 lanes per row) ------------------
    {
        const int row = t >> 4, part = t & 15;
        const float* xr = xblk + row * CD + part * 16;
        const float* br = wqbk + part * 16;
        float a = 0.f;
        #pragma unroll
        for (int i = 0; i < 4; ++i) {
            float4 xv = *(const float4*)&xr[i * 4];
            float4 bvv = *(const float4*)&br[i * 4];
            a = fmaf(xv.x, bvv.x, a); a = fmaf(xv.y, bvv.y, a);
            a = fmaf(xv.z, bvv.z, a); a = fmaf(xv.w, bvv.w, a);
        }
        a += __shfl_xor(a, 1);
        a += __shfl_xor(a, 2);
        a += __shfl_xor(a, 4);
        a += __shfl_xor(a, 8);
        if (part == 0) sxb[row] = a;
    }
    __syncthreads();

    // ---- Phase T: Tt[d][i] = sum_c Mt[d][c]*X[i][c]  (split, 3 terms) -----
    // Wave w: d-tile w, all 4 token tiles. 96 MFMAs/wave.
    {
        f4_t acc[4];
        const f4_t z = {0.f, 0.f, 0.f, 0.f};
        #pragma unroll
        for (int a = 0; a < 4; ++a) acc[a] = z;

        const int drow = wave * 16 + lane15;
        #pragma unroll
        for (int kk = 0; kk < 8; ++kk) {
            const int k0 = kk * 32 + quad * 8;
            const int mo = drow * CD + k0;
            bfrag_t Ah = *(const bfrag_t*)(Mthi + mo);
            bfrag_t Al = *(const bfrag_t*)(Mtlo + mo);
            bfrag_t Bh[4], Bl[4];
            #pragma unroll
            for (int nt = 0; nt < 4; ++nt) {
                const int xo = (nt * 16 + lane15) * XST + k0;
                Bh[nt] = *(const bfrag_t*)(sXhi + xo);
                Bl[nt] = *(const bfrag_t*)(sXlo + xo);
            }
            #pragma unroll
            for (int nt = 0; nt < 4; ++nt) {
                acc[nt] = MFMA(Ah, Bh[nt], acc[nt]);
                acc[nt] = MFMA(Ah, Bl[nt], acc[nt]);
                acc[nt] = MFMA(Al, Bh[nt], acc[nt]);
            }
        }
        #pragma unroll
        for (int nt = 0; nt < 4; ++nt) {
            const int i  = nt * 16 + lane15;
            const int d0 = wave * 16 + quad * 4;
            ushort4 h4, l4;
            float f;
            f = acc[nt][0]; h4.x = f2bf(f); l4.x = f2bf(f - bf2f(h4.x));
            f = acc[nt][1]; h4.y = f2bf(f); l4.y = f2bf(f - bf2f(h4.y));
            f = acc[nt][2]; h4.z = f2bf(f); l4.z = f2bf(f - bf2f(h4.z));
            f = acc[nt][3]; h4.w = f2bf(f); l4.w = f2bf(f - bf2f(h4.w));
            *(ushort4*)&sThi[i * XST + d0] = h4;
            *(ushort4*)&sTlo[i * XST + d0] = l4;
        }
    }
    __syncthreads();

    // ---- Phase S: S[w][v] = sum_c T[w][c]*X[v][c] + xb[v]  (3 terms) ------
    // Wave w: m-tile w>>2, n-tile w&3. 24 MFMAs/wave.
    {
        f4_t acc = {0.f, 0.f, 0.f, 0.f};
        const int m0 = (wave >> 2) * 16;
        const int n0 = (wave & 3) * 16;
        #pragma unroll
        for (int kk = 0; kk < 8; ++kk) {
            const int k0 = kk * 32 + quad * 8;
            const int to = (m0 + lane15) * XST + k0;
            const int xo = (n0 + lane15) * XST + k0;
            bfrag_t Th = *(const bfrag_t*)(sThi + to);
            bfrag_t Tl = *(const bfrag_t*)(sTlo + to);
            bfrag_t Xh = *(const bfrag_t*)(sXhi + xo);
            bfrag_t Xl = *(const bfrag_t*)(sXlo + xo);
            acc = MFMA(Th, Xh, acc);
            acc = MFMA(Th, Xl, acc);
            acc = MFMA(Tl, Xh, acc);
        }
        const int v = n0 + lane15;
        const float xbv = sxb[v];
        #pragma unroll
        for (int r = 0; r < 4; ++r) {
            const int wtok = m0 + quad * 4 + r;
            sS[wtok * SST + v] = acc[r] + xbv;
        }
    }
    __syncthreads();

    // ---- Phase V: Vt[d][j] = sum_c Wvt[d][c]*Xhi[j][c] + bv[d] ------------
    // Wave w: d-tile w, 4 j-tiles. 32 MFMAs/wave. Overwrites T region.
    {
        f4_t acc[4];
        const f4_t z = {0.f, 0.f, 0.f, 0.f};
        #pragma unroll
        for (int a = 0; a < 4; ++a) acc[a] = z;

        const int drow = wave * 16 + lane15;
        #pragma unroll
        for (int kk = 0; kk < 8; ++kk) {
            const int k0 = kk * 32 + quad * 8;
            bfrag_t Af = *(const bfrag_t*)(Wvthi + drow * CD + k0);
            #pragma unroll
            for (int nt = 0; nt < 4; ++nt) {
                bfrag_t Bf = *(const bfrag_t*)(sXhi + (nt * 16 + lane15) * XST + k0);
                acc[nt] = MFMA(Af, Bf, acc[nt]);
            }
        }
        #pragma unroll
        for (int nt = 0; nt < 4; ++nt) {
            const int j = nt * 16 + lane15;
            #pragma unroll
            for (int r = 0; r < 4; ++r) {
                const int d = wave * 16 + quad * 4 + r;
                sVt[d * VST + j] = f2bf(acc[nt][r] + sbv[d]);
            }
        }
    }
    // ---- softmax over v: 16 lanes per row, 4 elements each ----------------
    {
        const int row = t >> 4, part = t & 15;
        float* srow = &sS[row * SST + part * 4];
        float e[4];
        float mx = fmaxf(fmaxf(srow[0], srow[1]), fmaxf(srow[2], srow[3]));
        mx = fmaxf(mx, __shfl_xor(mx, 1));
        mx = fmaxf(mx, __shfl_xor(mx, 2));
        mx = fmaxf(mx, __shfl_xor(mx, 4));
        mx = fmaxf(mx, __shfl_xor(mx, 8));
        float sum = 0.f;
        #pragma unroll
        for (int u = 0; u < 4; ++u) { e[u] = __expf(srow[u] - mx); sum += e[u]; }
        sum += __shfl_xor(sum, 1);
        sum += __shfl_xor(sum, 2);
        sum += __shfl_xor(sum, 4);
        sum += __shfl_xor(sum, 8);
        float inv = 1.0f / sum;
        #pragma unroll
        for (int u = 0; u < 4; ++u) srow[u] = e[u] * inv;
    }
    __syncthreads();

    // ---- Phase PV: out[w][d] = (sum_j P[w][j]*Vt[d][j]) * x[w][d] ---------
    // Wave w: m-tile w&3, d-tiles (w>>2)*4 .. +3. 8 MFMAs/wave.
    {
        f4_t acc[4];
        const f4_t z = {0.f, 0.f, 0.f, 0.f};
        #pragma unroll
        for (int a = 0; a < 4; ++a) acc[a] = z;

        const int m0 = (wave & 3) * 16;
        const int nbase = (wave >> 2) * 64;
        #pragma unroll
        for (int kk = 0; kk < 2; ++kk) {
            const int k0 = kk * 32 + quad * 8;
            const float* p = &sS[(m0 + lane15) * SST + k0];
            f4_t p0 = *(const f4_t*)p;
            f4_t p1 = *(const f4_t*)(p + 4);
            bfrag_t Af;
            Af[0] = (short)f2bf(p0[0]); Af[1] = (short)f2bf(p0[1]);
            Af[2] = (short)f2bf(p0[2]); Af[3] = (short)f2bf(p0[3]);
            Af[4] = (short)f2bf(p1[0]); Af[5] = (short)f2bf(p1[1]);
            Af[6] = (short)f2bf(p1[2]); Af[7] = (short)f2bf(p1[3]);
            #pragma unroll
            for (int nt = 0; nt < 4; ++nt) {
                bfrag_t Bf = *(const bfrag_t*)(sVt + (nbase + nt * 16 + lane15) * VST + k0);
                acc[nt] = MFMA(Af, Bf, acc[nt]);
            }
        }
        #pragma unroll
        for (int nt = 0; nt < 4; ++nt) {
            const int d = nbase + nt * 16 + lane15;
            #pragma unroll
            for (int r = 0; r < 4; ++r) {
                const int wtok = m0 + quad * 4 + r;
                float g = xblk[wtok * CD + d];
                oblk[wtok * CD + d] = acc[nt][r] * g;
            }
        }
    }
}

extern "C" void kernel_launch(void* const* d_in, const int* in_sizes, int n_in,
                              void* d_out, int out_size, void* d_ws, size_t ws_size,
                              hipStream_t stream) {
    const float* x  = (const float*)d_in[0];
    const float* wq = (const float*)d_in[1];
    // d_in[2] = bq: row-constant in softmax -> provably unused
    const float* wk = (const float*)d_in[3];
    const float* bk = (const float*)d_in[4];
    const float* wv = (const float*)d_in[5];
    const float* bv = (const float*)d_in[6];
    float* out = (float*)d_out;

    char* ws = (char*)d_ws;
    u16* Mthi   = (u16*)ws;                         // 128 KB
    u16* Mtlo   = (u16*)(ws + (128 << 10));         // 128 KB
    u16* Wvthi  = (u16*)(ws + (256 << 10));         // 128 KB
    float* wqbk = (float*)(ws + (384 << 10));       // 1 KB

    prep_m<<<128, 256, 0, stream>>>(wq, wk, Mthi, Mtlo);
    prep_v<<<16, 256, 0, stream>>>(wv, Wvthi);
    prep_b<<<16, 256, 0, stream>>>(wq, bk, wqbk);

    const size_t lds = (size_t)(4 * WD * XST * sizeof(u16)) +
                       (WD * SST + WD + CD) * sizeof(float);
    hipFuncSetAttribute((const void*)attn_kernel,
                        hipFuncAttributeMaxDynamicSharedMemorySize, (int)lds);
    attn_kernel<<<NBH, 1024, lds, stream>>>(x, Mthi, Mtlo, Wvthi, wqbk, bv, out);
}